// Round 1
// baseline (1483.875 us; speedup 1.0000x reference)
//
#include <hip/hip_runtime.h>

#define N_NODES 100000
#define N_EDGES 1600000
#define D 64

// ---------------------------------------------------------------- zero d_out
__global__ __launch_bounds__(256) void zero_kernel(float4* __restrict__ out, int n4) {
    int i = blockIdx.x * blockDim.x + threadIdx.x;
    if (i < n4) out[i] = make_float4(0.f, 0.f, 0.f, 0.f);
}

// ------------------------------------------------- scatter: out[dst] += feat[src]
// One thread per (edge, float4-chunk): 16 chunks of 4 floats = 64 features.
__global__ __launch_bounds__(256) void scatter_kernel(const float* __restrict__ feat,
                                                      const int* __restrict__ src,
                                                      const int* __restrict__ dst,
                                                      float* __restrict__ out) {
    int t = blockIdx.x * blockDim.x + threadIdx.x;
    int e = t >> 4;
    int q = t & 15;
    if (e >= N_EDGES) return;
    int s = src[e];
    int d = dst[e];
    const float4 v = *reinterpret_cast<const float4*>(feat + (size_t)s * D + q * 4);
    float* o = out + (size_t)d * D + q * 4;
    // unsafeAtomicAdd -> global_atomic_add_f32 (HW fp32 atomic, no CAS loop)
    unsafeAtomicAdd(o + 0, v.x);
    unsafeAtomicAdd(o + 1, v.y);
    unsafeAtomicAdd(o + 2, v.z);
    unsafeAtomicAdd(o + 3, v.w);
}

// ------------------------------------------- in-place linear: io = io @ W^T + b
// Block = 256 threads = 4 rows x 64 cols. W in LDS, stride 65 (bank-conflict-free:
// lane c reads word c*65+k -> bank (c+k)%32, 2-way aliasing across 64 lanes = free).
// Row reads are wave-uniform broadcasts. In-place safe: block reads rows to LDS,
// syncs, writes only those rows.
__global__ __launch_bounds__(256) void linear_kernel(float* __restrict__ io,
                                                     const float* __restrict__ W,
                                                     const float* __restrict__ b) {
    __shared__ float wLds[D * 65];
    __shared__ float bLds[D];
    __shared__ float rowLds[4][D];

    for (int i = threadIdx.x; i < D * D; i += 256) {
        int c = i >> 6;
        int k = i & 63;
        wLds[c * 65 + k] = W[i];
    }
    if (threadIdx.x < D) bLds[threadIdx.x] = b[threadIdx.x];
    __syncthreads();

    const int c  = threadIdx.x & 63;   // output column
    const int rl = threadIdx.x >> 6;   // local row 0..3
    const int nGroups = (N_NODES + 3) / 4;

    for (int g = blockIdx.x; g < nGroups; g += gridDim.x) {
        const int rowBase = g * 4;
        // stage 4 rows (coalesced: thread i loads element (i>>6, i&63))
        {
            int r = rowBase + (threadIdx.x >> 6);
            if (r < N_NODES)
                rowLds[threadIdx.x >> 6][threadIdx.x & 63] =
                    io[(size_t)r * D + (threadIdx.x & 63)];
        }
        __syncthreads();

        const int r = rowBase + rl;
        float acc = bLds[c];
        const float* __restrict__ wrow = &wLds[c * 65];
        const float* __restrict__ row  = rowLds[rl];
#pragma unroll
        for (int k = 0; k < D; ++k) acc += row[k] * wrow[k];
        if (r < N_NODES) io[(size_t)r * D + c] = acc;
        __syncthreads();  // protect rowLds before next group's load
    }
}

extern "C" void kernel_launch(void* const* d_in, const int* in_sizes, int n_in,
                              void* d_out, int out_size, void* d_ws, size_t ws_size,
                              hipStream_t stream) {
    const float* feat = (const float*)d_in[0];
    const int*   src  = (const int*)d_in[1];
    const int*   dst  = (const int*)d_in[2];
    const float* W    = (const float*)d_in[3];
    const float* b    = (const float*)d_in[4];
    float* out = (float*)d_out;

    const int n4 = N_NODES * D / 4;  // 1.6M float4s
    zero_kernel<<<(n4 + 255) / 256, 256, 0, stream>>>((float4*)out, n4);

    const long long scatterThreads = (long long)N_EDGES * 16;
    scatter_kernel<<<(int)((scatterThreads + 255) / 256), 256, 0, stream>>>(feat, src, dst, out);

    linear_kernel<<<1024, 256, 0, stream>>>(out, W, b);
}

// Round 2
// 481.318 us; speedup vs baseline: 3.0829x; 3.0829x over previous
//
#include <hip/hip_runtime.h>

#define NN 100000
#define NE 1600000
#define D 64
#define NBLK ((NN + 255) / 256)   // 391 scan blocks

// ---------------- A: h = feat @ W^T (no bias) ------------------------------
// One wave per row (grid-stride). Lane c holds W[c][0..63] in 64 VGPRs.
// Row reads are wave-uniform (readfirstlane-derived index) -> scalar-cache /
// broadcast loads; 64 v_fma per row per wave.
__global__ __launch_bounds__(256) void transform_kernel(const float* __restrict__ feat,
                                                        const float* __restrict__ W,
                                                        float* __restrict__ h) {
    const int lane = threadIdx.x & 63;
    const int wave = __builtin_amdgcn_readfirstlane(threadIdx.x >> 6);
    float wreg[D];
    const float4* __restrict__ W4 = (const float4*)W;
#pragma unroll
    for (int i = 0; i < 16; ++i) {
        float4 w4 = W4[lane * 16 + i];
        wreg[4 * i + 0] = w4.x; wreg[4 * i + 1] = w4.y;
        wreg[4 * i + 2] = w4.z; wreg[4 * i + 3] = w4.w;
    }
    const int stride = gridDim.x * 4;
    for (int r = blockIdx.x * 4 + wave; r < NN; r += stride) {
        const float* __restrict__ row = feat + (size_t)r * D;
        float acc = 0.f;
#pragma unroll
        for (int k = 0; k < D; ++k) acc += row[k] * wreg[k];
        h[(size_t)r * D + lane] = acc;
    }
}

// ---------------- B: zero degree counters + cursors ------------------------
__global__ __launch_bounds__(256) void zero_kernel(int* __restrict__ counts,
                                                   int* __restrict__ cursor) {
    int i = blockIdx.x * 256 + threadIdx.x;
    if (i < NN) { counts[i] = 0; cursor[i] = 0; }
}

// ---------------- C: degree count (int atomics) ----------------------------
__global__ __launch_bounds__(256) void count_kernel(const int* __restrict__ dst,
                                                    int* __restrict__ counts) {
    int e = blockIdx.x * 256 + threadIdx.x;
    if (e < NE) atomicAdd(&counts[dst[e]], 1);
}

// ---------------- D/E/F: exclusive scan of counts -> offs ------------------
__global__ __launch_bounds__(256) void scan1_kernel(const int* __restrict__ counts,
                                                    int* __restrict__ offs,
                                                    int* __restrict__ bsums) {
    __shared__ int s[256];
    int t = threadIdx.x;
    int i = blockIdx.x * 256 + t;
    int v = (i < NN) ? counts[i] : 0;
    s[t] = v;
    __syncthreads();
    for (int o = 1; o < 256; o <<= 1) {
        int x = (t >= o) ? s[t - o] : 0;
        __syncthreads();
        s[t] += x;
        __syncthreads();
    }
    if (i < NN) offs[i] = s[t] - v;              // exclusive within block
    if (t == 255) bsums[blockIdx.x] = s[255];    // block total
}

__global__ __launch_bounds__(512) void scan2_kernel(int* __restrict__ bsums) {
    __shared__ int s[512];
    int t = threadIdx.x;
    int v = (t < NBLK) ? bsums[t] : 0;
    s[t] = v;
    __syncthreads();
    for (int o = 1; o < 512; o <<= 1) {
        int x = (t >= o) ? s[t - o] : 0;
        __syncthreads();
        s[t] += x;
        __syncthreads();
    }
    if (t < NBLK) bsums[t] = s[t] - v;           // exclusive block offsets
}

__global__ __launch_bounds__(256) void scan3_kernel(int* __restrict__ offs,
                                                    const int* __restrict__ bsums) {
    int i = blockIdx.x * 256 + threadIdx.x;
    if (i < NN) offs[i] += bsums[blockIdx.x];
}

// ---------------- G: bin edges by dst (CSR fill) ---------------------------
__global__ __launch_bounds__(256) void fill_kernel(const int* __restrict__ src,
                                                   const int* __restrict__ dst,
                                                   const int* __restrict__ offs,
                                                   int* __restrict__ cursor,
                                                   int* __restrict__ binned) {
    int e = blockIdx.x * 256 + threadIdx.x;
    if (e >= NE) return;
    int d = dst[e];
    int p = offs[d] + atomicAdd(&cursor[d], 1);
    binned[p] = src[e];
}

// ---------------- H: out[v] = b + sum_{u in in(v)} h[u] --------------------
// One wave per node; lane = feature column. Edge indices for the row are
// loaded with ONE coalesced read per 64 edges, then shfl-broadcast.
__global__ __launch_bounds__(256) void gather_kernel(const float* __restrict__ h,
                                                     const int* __restrict__ binned,
                                                     const int* __restrict__ offs,
                                                     const int* __restrict__ counts,
                                                     const float* __restrict__ bias,
                                                     float* __restrict__ out) {
    const int lane = threadIdx.x & 63;
    const int wave = threadIdx.x >> 6;
    const int stride = gridDim.x * 4;
    const float bv = bias[lane];
    for (int v = blockIdx.x * 4 + wave; v < NN; v += stride) {
        const int start = offs[v];
        const int deg = counts[v];
        float acc = bv;
        for (int base = 0; base < deg; base += 64) {
            int rem = deg - base; if (rem > 64) rem = 64;
            int idx = (lane < rem) ? binned[start + base + lane] : 0;
            for (int j = 0; j < rem; ++j) {
                int u = __shfl(idx, j, 64);
                acc += h[(size_t)u * D + lane];
            }
        }
        out[(size_t)v * D + lane] = acc;
    }
}

extern "C" void kernel_launch(void* const* d_in, const int* in_sizes, int n_in,
                              void* d_out, int out_size, void* d_ws, size_t ws_size,
                              hipStream_t stream) {
    const float* feat = (const float*)d_in[0];
    const int*   src  = (const int*)d_in[1];
    const int*   dst  = (const int*)d_in[2];
    const float* W    = (const float*)d_in[3];
    const float* b    = (const float*)d_in[4];
    float* out = (float*)d_out;

    // workspace layout (33.2 MB total)
    float* h      = (float*)d_ws;                 // NN*D floats
    int*   counts = (int*)(h + (size_t)NN * D);   // NN
    int*   offs   = counts + NN;                  // NN
    int*   cursor = offs + NN;                    // NN
    int*   bsums  = cursor + NN;                  // 512 (NBLK used)
    int*   binned = bsums + 512;                  // NE

    transform_kernel<<<512, 256, 0, stream>>>(feat, W, h);
    zero_kernel<<<NBLK, 256, 0, stream>>>(counts, cursor);
    count_kernel<<<(NE + 255) / 256, 256, 0, stream>>>(dst, counts);
    scan1_kernel<<<NBLK, 256, 0, stream>>>(counts, offs, bsums);
    scan2_kernel<<<1, 512, 0, stream>>>(bsums);
    scan3_kernel<<<NBLK, 256, 0, stream>>>(offs, bsums);
    fill_kernel<<<(NE + 255) / 256, 256, 0, stream>>>(src, dst, offs, cursor, binned);
    gather_kernel<<<1024, 256, 0, stream>>>(h, binned, offs, counts, b, out);
}

// Round 3
// 380.751 us; speedup vs baseline: 3.8972x; 1.2641x over previous
//
#include <hip/hip_runtime.h>

#define NN 100000
#define NE 1600000
#define D 64
#define NBLK ((NN + 255) / 256)   // 391 scan blocks

// ---------------- A: h = feat @ W^T (no bias) ------------------------------
__global__ __launch_bounds__(256) void transform_kernel(const float* __restrict__ feat,
                                                        const float* __restrict__ W,
                                                        float* __restrict__ h) {
    const int lane = threadIdx.x & 63;
    const int wave = __builtin_amdgcn_readfirstlane(threadIdx.x >> 6);
    float wreg[D];
    const float4* __restrict__ W4 = (const float4*)W;
#pragma unroll
    for (int i = 0; i < 16; ++i) {
        float4 w4 = W4[lane * 16 + i];
        wreg[4 * i + 0] = w4.x; wreg[4 * i + 1] = w4.y;
        wreg[4 * i + 2] = w4.z; wreg[4 * i + 3] = w4.w;
    }
    const int stride = gridDim.x * 4;
    for (int r = blockIdx.x * 4 + wave; r < NN; r += stride) {
        const float* __restrict__ row = feat + (size_t)r * D;
        float acc = 0.f;
#pragma unroll
        for (int k = 0; k < D; ++k) acc += row[k] * wreg[k];
        h[(size_t)r * D + lane] = acc;
    }
}

// ---------------- B: zero degree counters ----------------------------------
__global__ __launch_bounds__(256) void zero_kernel(int* __restrict__ counts) {
    int i = blockIdx.x * 256 + threadIdx.x;
    if (i < NN) counts[i] = 0;
}

// ---------------- C: degree count (int atomics) ----------------------------
__global__ __launch_bounds__(256) void count_kernel(const int* __restrict__ dst,
                                                    int* __restrict__ counts) {
    int e = blockIdx.x * 256 + threadIdx.x;
    if (e < NE) atomicAdd(&counts[dst[e]], 1);
}

// ---------------- D/E/F: exclusive scan of counts -> offs (+cursor copy) ---
__global__ __launch_bounds__(256) void scan1_kernel(const int* __restrict__ counts,
                                                    int* __restrict__ offs,
                                                    int* __restrict__ bsums) {
    __shared__ int s[256];
    int t = threadIdx.x;
    int i = blockIdx.x * 256 + t;
    int v = (i < NN) ? counts[i] : 0;
    s[t] = v;
    __syncthreads();
    for (int o = 1; o < 256; o <<= 1) {
        int x = (t >= o) ? s[t - o] : 0;
        __syncthreads();
        s[t] += x;
        __syncthreads();
    }
    if (i < NN) offs[i] = s[t] - v;
    if (t == 255) bsums[blockIdx.x] = s[255];
}

__global__ __launch_bounds__(512) void scan2_kernel(int* __restrict__ bsums) {
    __shared__ int s[512];
    int t = threadIdx.x;
    int v = (t < NBLK) ? bsums[t] : 0;
    s[t] = v;
    __syncthreads();
    for (int o = 1; o < 512; o <<= 1) {
        int x = (t >= o) ? s[t - o] : 0;
        __syncthreads();
        s[t] += x;
        __syncthreads();
    }
    if (t < NBLK) bsums[t] = s[t] - v;
}

__global__ __launch_bounds__(256) void scan3_kernel(int* __restrict__ offs,
                                                    int* __restrict__ cursor,
                                                    const int* __restrict__ bsums) {
    int i = blockIdx.x * 256 + threadIdx.x;
    if (i < NN) {
        int o = offs[i] + bsums[blockIdx.x];
        offs[i] = o;
        cursor[i] = o;   // fill's fetch-add cursor starts at the offset
    }
}

// ---------------- G: bin edges by dst (CSR fill) ---------------------------
__global__ __launch_bounds__(256) void fill_kernel(const int* __restrict__ src,
                                                   const int* __restrict__ dst,
                                                   int* __restrict__ cursor,
                                                   int* __restrict__ binned) {
    int e = blockIdx.x * 256 + threadIdx.x;
    if (e >= NE) return;
    int p = atomicAdd(&cursor[dst[e]], 1);
    binned[p] = src[e];
}

// ---------------- H: out[v] = b + sum_{u in in(v)} h[u] --------------------
// Lane layout: slot = lane>>4 (edge slot 0..3), c4 = lane&15 (float4 col grp).
// 8 edges per iteration, 2 independent float4 loads/lane in flight (MLP).
__global__ __launch_bounds__(256) void gather_kernel(const float4* __restrict__ h4,
                                                     const int* __restrict__ binned,
                                                     const int* __restrict__ offs,
                                                     const int* __restrict__ counts,
                                                     const float4* __restrict__ bias4,
                                                     float4* __restrict__ out4) {
    const int lane = threadIdx.x & 63;
    const int slot = lane >> 4;
    const int c4   = lane & 15;
    const int wave = threadIdx.x >> 6;
    const int stride = gridDim.x * 4;
    const float4 bv = bias4[c4];

    for (int v = blockIdx.x * 4 + wave; v < NN; v += stride) {
        const int start = offs[v];
        const int deg   = counts[v];
        float4 a0 = {0.f, 0.f, 0.f, 0.f};
        float4 a1 = {0.f, 0.f, 0.f, 0.f};

        for (int base = 0; base < deg; base += 64) {
            int rem = deg - base; if (rem > 64) rem = 64;
            int idx = (lane < rem) ? binned[start + base + lane] : 0;
            int jfull = rem & ~7;
            int j = 0;
            for (; j < jfull; j += 8) {
                int u0 = __shfl(idx, j + slot, 64);
                int u1 = __shfl(idx, j + 4 + slot, 64);
                float4 v0 = h4[(size_t)u0 * 16 + c4];
                float4 v1 = h4[(size_t)u1 * 16 + c4];
                a0.x += v0.x; a0.y += v0.y; a0.z += v0.z; a0.w += v0.w;
                a1.x += v1.x; a1.y += v1.y; a1.z += v1.z; a1.w += v1.w;
            }
            for (; j < rem; j += 4) {
                int u = __shfl(idx, j + slot, 64);
                if (j + slot < rem) {
                    float4 v0 = h4[(size_t)u * 16 + c4];
                    a0.x += v0.x; a0.y += v0.y; a0.z += v0.z; a0.w += v0.w;
                }
            }
        }

        a0.x += a1.x; a0.y += a1.y; a0.z += a1.z; a0.w += a1.w;
        // reduce across the 4 edge slots (xor 16, 32)
#pragma unroll
        for (int off = 16; off <= 32; off <<= 1) {
            a0.x += __shfl_xor(a0.x, off, 64);
            a0.y += __shfl_xor(a0.y, off, 64);
            a0.z += __shfl_xor(a0.z, off, 64);
            a0.w += __shfl_xor(a0.w, off, 64);
        }
        if (slot == 0) {
            float4 r;
            r.x = a0.x + bv.x; r.y = a0.y + bv.y;
            r.z = a0.z + bv.z; r.w = a0.w + bv.w;
            out4[(size_t)v * 16 + c4] = r;
        }
    }
}

extern "C" void kernel_launch(void* const* d_in, const int* in_sizes, int n_in,
                              void* d_out, int out_size, void* d_ws, size_t ws_size,
                              hipStream_t stream) {
    const float* feat = (const float*)d_in[0];
    const int*   src  = (const int*)d_in[1];
    const int*   dst  = (const int*)d_in[2];
    const float* W    = (const float*)d_in[3];
    const float* b    = (const float*)d_in[4];
    float* out = (float*)d_out;

    float* h      = (float*)d_ws;                 // NN*D floats
    int*   counts = (int*)(h + (size_t)NN * D);   // NN
    int*   offs   = counts + NN;                  // NN
    int*   cursor = offs + NN;                    // NN
    int*   bsums  = cursor + NN;                  // 512
    int*   binned = bsums + 512;                  // NE

    transform_kernel<<<1024, 256, 0, stream>>>(feat, W, h);
    zero_kernel<<<NBLK, 256, 0, stream>>>(counts);
    count_kernel<<<(NE + 255) / 256, 256, 0, stream>>>(dst, counts);
    scan1_kernel<<<NBLK, 256, 0, stream>>>(counts, offs, bsums);
    scan2_kernel<<<1, 512, 0, stream>>>(bsums);
    scan3_kernel<<<NBLK, 256, 0, stream>>>(offs, cursor, bsums);
    fill_kernel<<<(NE + 255) / 256, 256, 0, stream>>>(src, dst, cursor, binned);
    gather_kernel<<<2048, 256, 0, stream>>>((const float4*)h, binned, offs, counts,
                                            (const float4*)b, (float4*)out);
}

// Round 4
// 255.052 us; speedup vs baseline: 5.8179x; 1.4928x over previous
//
#include <hip/hip_runtime.h>

#define NN 100000
#define NE 1600000
#define D 64
#define NBKT 782            // ceil(NN / 128) coarse buckets
#define BKT_SHIFT 7
#define BKT_MASK 127
#define SRC_MASK 0x1FFFF    // src < 100000 < 2^17
#define EPB 8192            // edges per block in P1/P2
#define NPB ((NE + EPB - 1) / EPB)   // 196 blocks
#define P3CAP 3072          // max edges per bucket staged in LDS (mean 2048, sd 45)

// ---------------- A: h = feat @ W^T (no bias) ------------------------------
__global__ __launch_bounds__(256) void transform_kernel(const float* __restrict__ feat,
                                                        const float* __restrict__ W,
                                                        float* __restrict__ h) {
    const int lane = threadIdx.x & 63;
    const int wave = __builtin_amdgcn_readfirstlane(threadIdx.x >> 6);
    float wreg[D];
    const float4* __restrict__ W4 = (const float4*)W;
#pragma unroll
    for (int i = 0; i < 16; ++i) {
        float4 w4 = W4[lane * 16 + i];
        wreg[4 * i + 0] = w4.x; wreg[4 * i + 1] = w4.y;
        wreg[4 * i + 2] = w4.z; wreg[4 * i + 3] = w4.w;
    }
    const int stride = gridDim.x * 4;
    for (int r = blockIdx.x * 4 + wave; r < NN; r += stride) {
        const float* __restrict__ row = feat + (size_t)r * D;
        float acc = 0.f;
#pragma unroll
        for (int k = 0; k < D; ++k) acc += row[k] * wreg[k];
        h[(size_t)r * D + lane] = acc;
    }
}

// ---------------- zero coarse bucket counters ------------------------------
__global__ __launch_bounds__(1024) void zerob_kernel(int* __restrict__ bucketCnt) {
    if (threadIdx.x < NBKT) bucketCnt[threadIdx.x] = 0;
}

// ---------------- P1: coarse histogram (LDS-aggregated) --------------------
__global__ __launch_bounds__(256) void p1_hist(const int* __restrict__ dst,
                                               int* __restrict__ bucketCnt) {
    __shared__ int hist[NBKT];
    for (int i = threadIdx.x; i < NBKT; i += 256) hist[i] = 0;
    __syncthreads();
    const int lo = blockIdx.x * EPB;
    const int hi = min(lo + EPB, NE);
    for (int e = lo + threadIdx.x; e < hi; e += 256)
        atomicAdd(&hist[dst[e] >> BKT_SHIFT], 1);
    __syncthreads();
    for (int i = threadIdx.x; i < NBKT; i += 256) {
        int c = hist[i];
        if (c) atomicAdd(&bucketCnt[i], c);
    }
}

// ---------------- scanB: exclusive scan of 782 bucket counts ---------------
__global__ __launch_bounds__(1024) void scanb_kernel(const int* __restrict__ bucketCnt,
                                                     int* __restrict__ bucketBase,
                                                     int* __restrict__ cursor) {
    __shared__ int s[1024];
    int t = threadIdx.x;
    int v = (t < NBKT) ? bucketCnt[t] : 0;
    s[t] = v;
    __syncthreads();
    for (int o = 1; o < 1024; o <<= 1) {
        int x = (t >= o) ? s[t - o] : 0;
        __syncthreads();
        s[t] += x;
        __syncthreads();
    }
    if (t < NBKT) { int b = s[t] - v; bucketBase[t] = b; cursor[t] = b; }
}

// ---------------- P2: scatter packed edges into coarse buckets -------------
// Global returning atomics only per (block,bucket) pair; ranks via LDS.
__global__ __launch_bounds__(256) void p2_scatter(const int* __restrict__ src,
                                                  const int* __restrict__ dst,
                                                  int* __restrict__ cursor,
                                                  int* __restrict__ binned) {
    __shared__ int hist[NBKT];
    __shared__ int base[NBKT];
    for (int i = threadIdx.x; i < NBKT; i += 256) hist[i] = 0;
    __syncthreads();
    const int lo = blockIdx.x * EPB;
    const int hi = min(lo + EPB, NE);
    for (int e = lo + threadIdx.x; e < hi; e += 256)
        atomicAdd(&hist[dst[e] >> BKT_SHIFT], 1);
    __syncthreads();
    for (int i = threadIdx.x; i < NBKT; i += 256) {
        int c = hist[i];
        base[i] = c ? atomicAdd(&cursor[i], c) : 0;
        hist[i] = 0;
    }
    __syncthreads();
    for (int e = lo + threadIdx.x; e < hi; e += 256) {
        int dv = dst[e];
        int bkt = dv >> BKT_SHIFT;
        int r = atomicAdd(&hist[bkt], 1);
        binned[base[bkt] + r] = src[e] | ((dv & BKT_MASK) << 17);
    }
}

// ---------------- P3: fine bin within each bucket (all in LDS) -------------
// Rewrites binned in place (staged fully in LDS first); emits meta=(start,deg).
__global__ __launch_bounds__(256) void p3_bin(const int* __restrict__ bucketCnt,
                                              const int* __restrict__ bucketBase,
                                              int* __restrict__ binned,
                                              int2* __restrict__ meta) {
    __shared__ int ebuf[P3CAP];
    __shared__ int cnt[128];
    __shared__ int loff[128];
    __shared__ int cur[128];
    const int b = blockIdx.x;
    const int gbase = bucketBase[b];
    int sz = bucketCnt[b];
    if (sz > P3CAP) sz = P3CAP;   // 22-sigma guard, statistically impossible
    for (int i = threadIdx.x; i < sz; i += 256) ebuf[i] = binned[gbase + i];
    if (threadIdx.x < 128) cnt[threadIdx.x] = 0;
    __syncthreads();
    for (int i = threadIdx.x; i < sz; i += 256)
        atomicAdd(&cnt[(ebuf[i] >> 17) & BKT_MASK], 1);
    __syncthreads();
    const int t = threadIdx.x;
    const int v = (t < 128) ? cnt[t] : 0;
    if (t < 128) loff[t] = v;
    __syncthreads();
    for (int o = 1; o < 128; o <<= 1) {
        int x = (t < 128 && t >= o) ? loff[t - o] : 0;
        __syncthreads();
        if (t < 128) loff[t] += x;
        __syncthreads();
    }
    if (t < 128) {
        int ex = loff[t] - v;       // exclusive offset within bucket
        cur[t] = ex;
        int node = b * 128 + t;
        if (node < NN) meta[node] = make_int2(gbase + ex, v);
    }
    __syncthreads();
    for (int i = threadIdx.x; i < sz; i += 256) {
        int packed = ebuf[i];
        int r = atomicAdd(&cur[(packed >> 17) & BKT_MASK], 1);
        binned[gbase + r] = packed & SRC_MASK;
    }
}

// ---------------- gather: out[v] = b + sum h[src in-edges] -----------------
// Quarter-wave (16 lanes) per node; lane = float4 column group. 4 independent
// float4 loads in flight per lane; no cross-lane reduction needed.
__global__ __launch_bounds__(256) void gather_kernel(const float4* __restrict__ h4,
                                                     const int* __restrict__ binned,
                                                     const int2* __restrict__ meta,
                                                     const float4* __restrict__ bias4,
                                                     float4* __restrict__ out4) {
    const int lane = threadIdx.x & 63;
    const int c4   = lane & 15;        // float4 column group
    const int grp  = lane >> 4;        // node slot within wave (0..3)
    const int wave = threadIdx.x >> 6;
    const float4 bv = bias4[c4];
    const int stride = gridDim.x * 16;
    for (int v = blockIdx.x * 16 + wave * 4 + grp; v < NN; v += stride) {
        const int2 md = meta[v];       // (start, deg) — broadcast in group
        const int start = md.x, deg = md.y;
        float4 a0 = {0.f,0.f,0.f,0.f}, a1 = {0.f,0.f,0.f,0.f};
        float4 a2 = {0.f,0.f,0.f,0.f}, a3 = {0.f,0.f,0.f,0.f};
        for (int base = 0; base < deg; base += 16) {
            int rem = deg - base; if (rem > 16) rem = 16;
            int idx = (c4 < rem) ? binned[start + base + c4] : 0;
            int j = 0;
            for (; j + 4 <= rem; j += 4) {
                int u0 = __shfl(idx, grp * 16 + j + 0, 64);
                int u1 = __shfl(idx, grp * 16 + j + 1, 64);
                int u2 = __shfl(idx, grp * 16 + j + 2, 64);
                int u3 = __shfl(idx, grp * 16 + j + 3, 64);
                float4 x0 = h4[(size_t)u0 * 16 + c4];
                float4 x1 = h4[(size_t)u1 * 16 + c4];
                float4 x2 = h4[(size_t)u2 * 16 + c4];
                float4 x3 = h4[(size_t)u3 * 16 + c4];
                a0.x += x0.x; a0.y += x0.y; a0.z += x0.z; a0.w += x0.w;
                a1.x += x1.x; a1.y += x1.y; a1.z += x1.z; a1.w += x1.w;
                a2.x += x2.x; a2.y += x2.y; a2.z += x2.z; a2.w += x2.w;
                a3.x += x3.x; a3.y += x3.y; a3.z += x3.z; a3.w += x3.w;
            }
            for (; j < rem; ++j) {
                int u = __shfl(idx, grp * 16 + j, 64);
                float4 x = h4[(size_t)u * 16 + c4];
                a0.x += x.x; a0.y += x.y; a0.z += x.z; a0.w += x.w;
            }
        }
        float4 r;
        r.x = a0.x + a1.x + a2.x + a3.x + bv.x;
        r.y = a0.y + a1.y + a2.y + a3.y + bv.y;
        r.z = a0.z + a1.z + a2.z + a3.z + bv.z;
        r.w = a0.w + a1.w + a2.w + a3.w + bv.w;
        out4[(size_t)v * 16 + c4] = r;
    }
}

extern "C" void kernel_launch(void* const* d_in, const int* in_sizes, int n_in,
                              void* d_out, int out_size, void* d_ws, size_t ws_size,
                              hipStream_t stream) {
    const float* feat = (const float*)d_in[0];
    const int*   src  = (const int*)d_in[1];
    const int*   dst  = (const int*)d_in[2];
    const float* W    = (const float*)d_in[3];
    const float* b    = (const float*)d_in[4];
    float* out = (float*)d_out;

    // workspace layout (~32.8 MB)
    float* h        = (float*)d_ws;                   // NN*D floats  (25.6 MB)
    int*   binned   = (int*)(h + (size_t)NN * D);     // NE           (6.4 MB)
    int2*  meta     = (int2*)(binned + NE);           // NN           (0.8 MB)
    int*   bucketCnt  = (int*)(meta + NN);            // NBKT
    int*   bucketBase = bucketCnt + NBKT;             // NBKT
    int*   cursor     = bucketBase + NBKT;            // NBKT

    transform_kernel<<<1024, 256, 0, stream>>>(feat, W, h);
    zerob_kernel<<<1, 1024, 0, stream>>>(bucketCnt);
    p1_hist<<<NPB, 256, 0, stream>>>(dst, bucketCnt);
    scanb_kernel<<<1, 1024, 0, stream>>>(bucketCnt, bucketBase, cursor);
    p2_scatter<<<NPB, 256, 0, stream>>>(src, dst, cursor, binned);
    p3_bin<<<NBKT, 256, 0, stream>>>(bucketCnt, bucketBase, binned, meta);
    gather_kernel<<<6250, 256, 0, stream>>>((const float4*)h, binned, meta,
                                            (const float4*)b, (float4*)out);
}

// Round 5
// 208.011 us; speedup vs baseline: 7.1336x; 1.2261x over previous
//
#include <hip/hip_runtime.h>

#define NN 100000
#define NE 1600000
#define D 64
#define NBKT 782            // ceil(NN / 128) coarse buckets
#define BKT_SHIFT 7
#define BKT_MASK 127
#define SRC_MASK 0x1FFFF    // src < 100000 < 2^17
#define EPB 8192            // edges per block in P2
#define NPB ((NE + EPB - 1) / EPB)   // 196 blocks
#define BINCAP 2560         // padded slots per bucket (mean 2048, sd ~45 -> 11 sigma)
#define TROWS 16            // rows per block iteration in transform

// ---------------- A: h = feat @ W^T (no bias) ------------------------------
// 16 rows staged in LDS per iteration (coalesced float4), each wave computes
// 4 rows concurrently (4 independent FMA chains). W row held in 16 float4
// VGPRs per lane (lane = output column). Row reads are LDS broadcasts.
__global__ __launch_bounds__(256) void transform_kernel(const float* __restrict__ feat,
                                                        const float* __restrict__ W,
                                                        float* __restrict__ h) {
    __shared__ float4 rowLds[TROWS][16];
    const int lane = threadIdx.x & 63;
    const int wv   = threadIdx.x >> 6;
    float4 wreg[16];
    const float4* __restrict__ W4 = (const float4*)W;
#pragma unroll
    for (int i = 0; i < 16; ++i) wreg[i] = W4[lane * 16 + i];

    const int nTiles = NN / TROWS;   // 6250 exact
    for (int tile = blockIdx.x; tile < nTiles; tile += gridDim.x) {
        const int rowBase = tile * TROWS;
        rowLds[threadIdx.x >> 4][threadIdx.x & 15] =
            ((const float4*)(feat + (size_t)(rowBase + (threadIdx.x >> 4)) * D))[threadIdx.x & 15];
        __syncthreads();
        float a0 = 0.f, a1 = 0.f, a2 = 0.f, a3 = 0.f;
#pragma unroll
        for (int k4 = 0; k4 < 16; ++k4) {
            const float4 w  = wreg[k4];
            const float4 r0 = rowLds[wv * 4 + 0][k4];
            const float4 r1 = rowLds[wv * 4 + 1][k4];
            const float4 r2 = rowLds[wv * 4 + 2][k4];
            const float4 r3 = rowLds[wv * 4 + 3][k4];
            a0 += r0.x * w.x + r0.y * w.y + r0.z * w.z + r0.w * w.w;
            a1 += r1.x * w.x + r1.y * w.y + r1.z * w.z + r1.w * w.w;
            a2 += r2.x * w.x + r2.y * w.y + r2.z * w.z + r2.w * w.w;
            a3 += r3.x * w.x + r3.y * w.y + r3.z * w.z + r3.w * w.w;
        }
        const size_t ob = (size_t)(rowBase + wv * 4) * D + lane;
        h[ob]         = a0;
        h[ob + D]     = a1;
        h[ob + 2 * D] = a2;
        h[ob + 3 * D] = a3;
        __syncthreads();
    }
}

// ---------------- seed per-bucket cursors to region bases ------------------
__global__ __launch_bounds__(1024) void seed_kernel(int* __restrict__ cursor) {
    if (threadIdx.x < NBKT) cursor[threadIdx.x] = threadIdx.x * BINCAP;
}

// ---------------- P2: scatter packed edges into padded coarse buckets ------
// One global returning atomic per (block,bucket); ranks assigned in LDS.
__global__ __launch_bounds__(256) void p2_scatter(const int* __restrict__ src,
                                                  const int* __restrict__ dst,
                                                  int* __restrict__ cursor,
                                                  int* __restrict__ binned) {
    __shared__ int hist[NBKT];
    __shared__ int base[NBKT];
    for (int i = threadIdx.x; i < NBKT; i += 256) hist[i] = 0;
    __syncthreads();
    const int lo = blockIdx.x * EPB;
    const int hi = min(lo + EPB, NE);
    for (int e = lo + threadIdx.x; e < hi; e += 256)
        atomicAdd(&hist[dst[e] >> BKT_SHIFT], 1);
    __syncthreads();
    for (int i = threadIdx.x; i < NBKT; i += 256) {
        int c = hist[i];
        base[i] = c ? atomicAdd(&cursor[i], c) : 0;
        hist[i] = 0;
    }
    __syncthreads();
    for (int e = lo + threadIdx.x; e < hi; e += 256) {
        int dv = dst[e];
        int bkt = dv >> BKT_SHIFT;
        int r = atomicAdd(&hist[bkt], 1);
        binned[base[bkt] + r] = src[e] | ((dv & BKT_MASK) << 17);
    }
}

// ---------------- P3: fine bin within each bucket (all in LDS) -------------
__global__ __launch_bounds__(256) void p3_bin(const int* __restrict__ cursor,
                                              int* __restrict__ binned,
                                              int2* __restrict__ meta) {
    __shared__ int ebuf[BINCAP];
    __shared__ int cnt[128];
    __shared__ int loff[128];
    __shared__ int cur[128];
    const int b = blockIdx.x;
    const int gbase = b * BINCAP;
    int sz = cursor[b] - gbase;      // edges actually placed in this bucket
    if (sz > BINCAP) sz = BINCAP;    // 11-sigma guard
    for (int i = threadIdx.x; i < sz; i += 256) ebuf[i] = binned[gbase + i];
    if (threadIdx.x < 128) cnt[threadIdx.x] = 0;
    __syncthreads();
    for (int i = threadIdx.x; i < sz; i += 256)
        atomicAdd(&cnt[(ebuf[i] >> 17) & BKT_MASK], 1);
    __syncthreads();
    const int t = threadIdx.x;
    const int v = (t < 128) ? cnt[t] : 0;
    if (t < 128) loff[t] = v;
    __syncthreads();
    for (int o = 1; o < 128; o <<= 1) {
        int x = (t < 128 && t >= o) ? loff[t - o] : 0;
        __syncthreads();
        if (t < 128) loff[t] += x;
        __syncthreads();
    }
    if (t < 128) {
        int ex = loff[t] - v;
        cur[t] = ex;
        int node = b * 128 + t;
        if (node < NN) meta[node] = make_int2(gbase + ex, v);
    }
    __syncthreads();
    for (int i = threadIdx.x; i < sz; i += 256) {
        int packed = ebuf[i];
        int r = atomicAdd(&cur[(packed >> 17) & BKT_MASK], 1);
        binned[gbase + r] = packed & SRC_MASK;
    }
}

// ---------------- gather: out[v] = b + sum h[src in-edges] -----------------
// Quarter-wave (16 lanes) per node; lane = float4 column group. 4 independent
// float4 loads in flight per lane; no cross-lane reduction needed.
__global__ __launch_bounds__(256) void gather_kernel(const float4* __restrict__ h4,
                                                     const int* __restrict__ binned,
                                                     const int2* __restrict__ meta,
                                                     const float4* __restrict__ bias4,
                                                     float4* __restrict__ out4) {
    const int lane = threadIdx.x & 63;
    const int c4   = lane & 15;
    const int grp  = lane >> 4;
    const int wave = threadIdx.x >> 6;
    const float4 bv = bias4[c4];
    const int stride = gridDim.x * 16;
    for (int v = blockIdx.x * 16 + wave * 4 + grp; v < NN; v += stride) {
        const int2 md = meta[v];
        const int start = md.x, deg = md.y;
        float4 a0 = {0.f,0.f,0.f,0.f}, a1 = {0.f,0.f,0.f,0.f};
        float4 a2 = {0.f,0.f,0.f,0.f}, a3 = {0.f,0.f,0.f,0.f};
        for (int base = 0; base < deg; base += 16) {
            int rem = deg - base; if (rem > 16) rem = 16;
            int idx = (c4 < rem) ? binned[start + base + c4] : 0;
            int j = 0;
            for (; j + 4 <= rem; j += 4) {
                int u0 = __shfl(idx, grp * 16 + j + 0, 64);
                int u1 = __shfl(idx, grp * 16 + j + 1, 64);
                int u2 = __shfl(idx, grp * 16 + j + 2, 64);
                int u3 = __shfl(idx, grp * 16 + j + 3, 64);
                float4 x0 = h4[(size_t)u0 * 16 + c4];
                float4 x1 = h4[(size_t)u1 * 16 + c4];
                float4 x2 = h4[(size_t)u2 * 16 + c4];
                float4 x3 = h4[(size_t)u3 * 16 + c4];
                a0.x += x0.x; a0.y += x0.y; a0.z += x0.z; a0.w += x0.w;
                a1.x += x1.x; a1.y += x1.y; a1.z += x1.z; a1.w += x1.w;
                a2.x += x2.x; a2.y += x2.y; a2.z += x2.z; a2.w += x2.w;
                a3.x += x3.x; a3.y += x3.y; a3.z += x3.z; a3.w += x3.w;
            }
            for (; j < rem; ++j) {
                int u = __shfl(idx, grp * 16 + j, 64);
                float4 x = h4[(size_t)u * 16 + c4];
                a0.x += x.x; a0.y += x.y; a0.z += x.z; a0.w += x.w;
            }
        }
        float4 r;
        r.x = a0.x + a1.x + a2.x + a3.x + bv.x;
        r.y = a0.y + a1.y + a2.y + a3.y + bv.y;
        r.z = a0.z + a1.z + a2.z + a3.z + bv.z;
        r.w = a0.w + a1.w + a2.w + a3.w + bv.w;
        out4[(size_t)v * 16 + c4] = r;
    }
}

extern "C" void kernel_launch(void* const* d_in, const int* in_sizes, int n_in,
                              void* d_out, int out_size, void* d_ws, size_t ws_size,
                              hipStream_t stream) {
    const float* feat = (const float*)d_in[0];
    const int*   src  = (const int*)d_in[1];
    const int*   dst  = (const int*)d_in[2];
    const float* W    = (const float*)d_in[3];
    const float* b    = (const float*)d_in[4];
    float* out = (float*)d_out;

    // workspace layout (~34.4 MB)
    float* h      = (float*)d_ws;                   // NN*D floats (25.6 MB)
    int*   binned = (int*)(h + (size_t)NN * D);     // NBKT*BINCAP (8.0 MB)
    int2*  meta   = (int2*)(binned + NBKT * BINCAP);// NN (0.8 MB)
    int*   cursor = (int*)(meta + NN);              // NBKT

    transform_kernel<<<2048, 256, 0, stream>>>(feat, W, h);
    seed_kernel<<<1, 1024, 0, stream>>>(cursor);
    p2_scatter<<<NPB, 256, 0, stream>>>(src, dst, cursor, binned);
    p3_bin<<<NBKT, 256, 0, stream>>>(cursor, binned, meta);
    gather_kernel<<<6250, 256, 0, stream>>>((const float4*)h, binned, meta,
                                            (const float4*)b, (float4*)out);
}